// Round 6
// baseline (77.033 us; speedup 1.0000x reference)
//
#include <hip/hip_runtime.h>
#include <math.h>

// HypAgg (Poincare ball, c=1), 3 dispatches (graph dispatches ~free; round 2 vs 5
// showed dispatch count doesn't matter — latency structure does).
//   g_ij = att_ij * atanh(sn_ij)/sn_ij / den_ij
//   support_i = beta_i * ( -S_i x_i + beta_i Y_i ),  S=sum g*alpha, Y=sum g x_j
// hyp_prep: bf16 cast of x (row + transposed) + per-row stats -> ws   (64 blocks)
// hyp_pair: grid (64 i-tiles x 16 j-chunks of 64), NO LDS staging — MFMA frags
//           loaded straight from L2-resident Xb/Xbt; 6.3KB LDS -> 4 blocks/CU.
// hyp_exp : sums 16 partials + expmap (128 blocks).
// ws floats: Yp[16*131072] | Sp[16*1024] | st_x2[1024] | st_L[1024] | st_R[1024]
//            | Xb[1024*128 bf16] | Xbt[128*1024 bf16]

typedef short short4v __attribute__((ext_vector_type(4)));
typedef short short8v __attribute__((ext_vector_type(8)));
typedef float float4v __attribute__((ext_vector_type(4)));

static __device__ __forceinline__ short f2bf(float f) {
    unsigned u = __float_as_uint(f);
    u += 0x7fff + ((u >> 16) & 1);   // RNE; inputs never NaN here
    return (short)(u >> 16);
}
static __device__ __forceinline__ float rcpf(float x) { return __builtin_amdgcn_rcpf(x); }
static __device__ __forceinline__ short8v ld8(const unsigned short* p) {
    short4v lo = *(const short4v*)p;        // LDS: two b64 reads (8B-aligned)
    short4v hi = *(const short4v*)(p + 4);
    return (short8v){lo[0],lo[1],lo[2],lo[3],hi[0],hi[1],hi[2],hi[3]};
}
static __device__ __forceinline__ float dot4(float4v a, float4v b) {
    return a[0]*b[0] + a[1]*b[1] + a[2]*b[2] + a[3]*b[3];
}
static __device__ __forceinline__ float atanh_over(float pn) {   // atanh(min(pn,1-eps))/pn
    float uu = fminf(pn, 1.f - 1e-7f);
    return 0.5f * __logf((1.f + uu) * rcpf(1.f - uu)) * rcpf(pn);
}

// ---------------- kernel 1: bf16 materialize + stats ----------------
// 64 blocks x 256 threads; block handles 16 rows.
__global__ __launch_bounds__(256) void hyp_prep(
    const float* __restrict__ x, const float* __restrict__ w,
    const float* __restrict__ battp,
    unsigned short* __restrict__ Xb, unsigned short* __restrict__ Xbt,
    float* __restrict__ st_x2, float* __restrict__ st_L, float* __restrict__ st_R)
{
    __shared__ unsigned short sT[128 * 20];          // (dim, j) tile, pitch 20 (8B-align reads)
    __shared__ float sPx[16 * 36], sPl[16 * 36], sPr[16 * 36];
    const int t  = threadIdx.x;
    const int r0 = blockIdx.x * 16;
    const float4v* x4 = (const float4v*)x;
    const float4v* w4 = (const float4v*)w;

#pragma unroll
    for (int it = 0; it < 2; ++it) {
        int bid = t + it * 256;
        int jr = bid >> 5, dc = bid & 31;            // row 0..15, float4-col 0..31
        float4v v  = x4[(r0 + jr) * 32 + dc];
        float4v w1 = w4[dc], w2 = w4[32 + dc];
        short4v h = { f2bf(v[0]), f2bf(v[1]), f2bf(v[2]), f2bf(v[3]) };
        *(short4v*)&Xb[(r0 + jr) * 128 + dc * 4] = h;   // row-major global, coalesced
#pragma unroll
        for (int d = 0; d < 4; ++d)
            sT[(dc * 4 + d) * 20 + jr] = (unsigned short)h[d];
        sPx[jr * 36 + dc] = dot4(v, v);
        sPl[jr * 36 + dc] = dot4(v, w1);
        sPr[jr * 36 + dc] = dot4(v, w2);
    }
    __syncthreads();
    {   // transposed global write: thread -> (dim = t>>1, half = t&1)
        int dim = t >> 1, h = t & 1;
        short8v vv = ld8(&sT[dim * 20 + h * 8]);
        *(short8v*)&Xbt[dim * 1024 + r0 + h * 8] = vv;
    }
    if (t < 16) {
        float x2 = 0.f, l = 0.f, r = 0.f;
#pragma unroll
        for (int k = 0; k < 8; ++k) {
            float4v a = *(float4v*)&sPx[t * 36 + k * 4];
            float4v b = *(float4v*)&sPl[t * 36 + k * 4];
            float4v c = *(float4v*)&sPr[t * 36 + k * 4];
            x2 += a[0] + a[1] + a[2] + a[3];
            l  += b[0] + b[1] + b[2] + b[3];
            r  += c[0] + c[1] + c[2] + c[3];
        }
        float pn = sqrtf(fmaxf(x2, 1e-15f));
        float f  = atanh_over(pn);
        st_x2[r0 + t] = x2;
        st_L [r0 + t] = l * f + battp[0];   // DenseAtt left + bias, logmap0-scaled
        st_R [r0 + t] = r * f;
    }
}

// ---------------- kernel 2: pairwise MFMA + scalar map, no staging ----------------
// grid (64, 16): 16-row i-tile x 64-col j-chunk. 4 blocks/CU.
__global__ __launch_bounds__(256, 4) void hyp_pair(
    const unsigned short* __restrict__ Xb, const unsigned short* __restrict__ Xbt,
    const float* __restrict__ adj,
    const float* __restrict__ st_x2, const float* __restrict__ st_L,
    const float* __restrict__ st_R,
    float* __restrict__ Yp, float* __restrict__ Sp)
{
    __shared__ unsigned short sW[16 * 68];   // g weights bf16 (16 i x 64 j, pitch 68)
    __shared__ float sSp[4 * 256];           // per-wave S slots [wave][i*16+n]

    const int t    = threadIdx.x;
    const int lane = t & 63;
    const int wave = t >> 6;
    const int n    = lane & 15;
    const int q    = lane >> 4;
    const int i0   = blockIdx.x * 16;
    const int c    = blockIdx.y;
    const int j0   = c * 64;
    const int jrow = j0 + wave * 16 + n;     // this lane's j (one per lane)

    // ---- all loads issued up front (independent; 4 blocks/CU hide latency) ----
    float x2j = st_x2[jrow];
    float rj  = st_R[jrow];
    float x2i4[4], li4[4], bi4[4], adjv[4];
#pragma unroll
    for (int r = 0; r < 4; ++r) {
        int i = i0 + q * 4 + r;
        x2i4[r] = st_x2[i];
        li4[r]  = st_L[i];
        adjv[r] = adj[i * 1024 + jrow];
    }
    short8v afrag[4], bfA[4];
#pragma unroll
    for (int kk = 0; kk < 4; ++kk) {
        afrag[kk] = *(const short8v*)&Xb[(i0 + n) * 128 + kk * 32 + q * 8];
        bfA  [kk] = *(const short8v*)&Xb[jrow * 128     + kk * 32 + q * 8];
    }
    short8v bfB[2][2];   // phase-B B-frags (Xbt), independent of sW — prefetch now
#pragma unroll
    for (int nsl = 0; nsl < 2; ++nsl) {
        int ns = wave * 2 + nsl;
#pragma unroll
        for (int kk = 0; kk < 2; ++kk)
            bfB[nsl][kk] = *(const short8v*)&Xbt[(ns * 16 + n) * 1024 + j0 + kk * 32 + q * 8];
    }
#pragma unroll
    for (int r = 0; r < 4; ++r) bi4[r] = 1.f - x2i4[r];

    // ---- phase A: G = X_I * X_J^T (16x16, K=128) ----
    float4v acc = (float4v){0.f, 0.f, 0.f, 0.f};
#pragma unroll
    for (int kk = 0; kk < 4; ++kk)
        acc = __builtin_amdgcn_mfma_f32_16x16x32_bf16(afrag[kk], bfA[kk], acc, 0, 0, 0);

    // ---- per-pair scalar map -> sW, Sacc ----
    float Sacc[4];
#pragma unroll
    for (int r = 0; r < 4; ++r) {
        float G     = acc[r];
        float alpha = 1.f - 2.f * G + x2j;
        float den   = fmaxf(fmaf(x2i4[r], x2j, 1.f - 2.f * G), 1e-15f);
        float rdn   = rcpf(den);
        float bb    = bi4[r];
        float nn2   = alpha * alpha * x2i4[r] + bb * bb * x2j - 2.f * alpha * bb * G;
        float sn    = sqrtf(fmaxf(nn2 * rdn * rdn, 1e-15f));
        float tt    = atanh_over(sn);
        float z     = li4[r] + rj;                 // sigmoid arg (bias folded in li)
        float sig   = rcpf(1.f + __expf(-z));
        float g     = sig * adjv[r] * tt * rdn;
        Sacc[r]     = g * alpha;
        sW[(q * 4 + r) * 68 + wave * 16 + n] = (unsigned short)f2bf(g);
    }
    __syncthreads();   // B1: sW ready

    // ---- phase B: Y += W(16x64) * X_J(64x128) ----
    float4v accB[2];
    accB[0] = (float4v){0.f, 0.f, 0.f, 0.f};
    accB[1] = (float4v){0.f, 0.f, 0.f, 0.f};
#pragma unroll
    for (int nsl = 0; nsl < 2; ++nsl) {
#pragma unroll
        for (int kk = 0; kk < 2; ++kk) {
            short8v a = ld8(&sW[n * 68 + kk * 32 + q * 8]);
            accB[nsl] = __builtin_amdgcn_mfma_f32_16x16x32_bf16(a, bfB[nsl][kk], accB[nsl], 0, 0, 0);
        }
    }

    // ---- stores: Y partials + S via per-wave LDS slots ----
    float* Yc = Yp + c * 131072;
#pragma unroll
    for (int nsl = 0; nsl < 2; ++nsl) {
        int ns = wave * 2 + nsl;
#pragma unroll
        for (int r = 0; r < 4; ++r)
            Yc[(i0 + q * 4 + r) * 128 + ns * 16 + n] = accB[nsl][r];
    }
#pragma unroll
    for (int r = 0; r < 4; ++r)
        sSp[wave * 256 + (q * 4 + r) * 16 + n] = Sacc[r];
    __syncthreads();   // B2
    if (t < 16) {
        float s = 0.f;
#pragma unroll
        for (int wv = 0; wv < 4; ++wv)
#pragma unroll
            for (int k4 = 0; k4 < 4; ++k4) {
                float4v v = *(float4v*)&sSp[wv * 256 + t * 16 + k4 * 4];
                s += v[0] + v[1] + v[2] + v[3];
            }
        Sp[c * 1024 + i0 + t] = s;
    }
}

// ---------------- kernel 3: sum partials + expmap ----------------
// 128 blocks x 256 threads: 8 rows/block, 32 lanes/row, 4 dims/lane.
__global__ __launch_bounds__(256) void hyp_exp(
    const float* __restrict__ x, const float* __restrict__ Yp,
    const float* __restrict__ Sp, const float* __restrict__ st_x2,
    float* __restrict__ out)
{
    const int t   = threadIdx.x;
    const int row = blockIdx.x * 8 + (t >> 5);
    const int l32 = t & 31;
    float4v y = (float4v){0.f, 0.f, 0.f, 0.f};
    float S = 0.f;
#pragma unroll
    for (int c = 0; c < 16; ++c) {
        y += *(const float4v*)&Yp[c * 131072 + row * 128 + l32 * 4];
        S += Sp[c * 1024 + row];
    }
    float4v xa = ((const float4v*)x)[row * 32 + l32];
    float x2 = st_x2[row];
    float bE = fmaxf(1.f - x2, 1e-15f);
    float u[4], un2p = 0.f, xup = 0.f;
#pragma unroll
    for (int e = 0; e < 4; ++e) {
        u[e] = bE * (bE * y[e] - S * xa[e]);
        un2p += u[e] * u[e];
        xup  += xa[e] * u[e];
    }
#pragma unroll
    for (int m = 1; m < 32; m <<= 1) {
        un2p += __shfl_xor(un2p, m, 32);
        xup  += __shfl_xor(xup,  m, 32);
    }
    float un  = sqrtf(fmaxf(un2p, 1e-15f));
    float e2  = __expf(2.f * un * rcpf(bE));
    float th  = 1.f - 2.f * rcpf(e2 + 1.f);   // tanh(un/b)
    float s2  = th * rcpf(un);
    float xy  = s2 * xup;
    float y2s = th * th;
    float coef = 1.f + 2.f * xy + y2s;
    float den  = fmaxf(1.f + 2.f * xy + x2 * y2s, 1e-15f);
    float rd   = rcpf(den);
    float4v o = { (coef*xa[0] + bE*s2*u[0])*rd, (coef*xa[1] + bE*s2*u[1])*rd,
                  (coef*xa[2] + bE*s2*u[2])*rd, (coef*xa[3] + bE*s2*u[3])*rd };
    ((float4v*)out)[row * 32 + l32] = o;
}

extern "C" void kernel_launch(void* const* d_in, const int* in_sizes, int n_in,
                              void* d_out, int out_size, void* d_ws, size_t ws_size,
                              hipStream_t stream) {
    const float* x    = (const float*)d_in[0];
    const float* adj  = (const float*)d_in[1];
    const float* w    = (const float*)d_in[2];
    const float* batt = (const float*)d_in[3];
    float* out = (float*)d_out;

    float* Yp    = (float*)d_ws;            // 16 * 131072 floats
    float* Sp    = Yp + 16 * 131072;        // 16 * 1024
    float* st_x2 = Sp + 16 * 1024;          // 1024
    float* st_L  = st_x2 + 1024;            // 1024
    float* st_R  = st_L + 1024;             // 1024
    unsigned short* Xb  = (unsigned short*)(st_R + 1024);   // 1024*128 bf16
    unsigned short* Xbt = Xb + 1024 * 128;                  // 128*1024 bf16

    hipLaunchKernelGGL(hyp_prep, dim3(64), dim3(256), 0, stream,
                       x, w, batt, Xb, Xbt, st_x2, st_L, st_R);
    hipLaunchKernelGGL(hyp_pair, dim3(64, 16), dim3(256), 0, stream,
                       Xb, Xbt, adj, st_x2, st_L, st_R, Yp, Sp);
    hipLaunchKernelGGL(hyp_exp, dim3(128), dim3(256), 0, stream,
                       x, Yp, Sp, st_x2, out);
}

// Round 7
// 76.511 us; speedup vs baseline: 1.0068x; 1.0068x over previous
//
#include <hip/hip_runtime.h>
#include <math.h>

// HypAgg (Poincare ball, c=1), 2 dispatches.
//   g_ij = att_ij * atanh(sn_ij)/sn_ij / den_ij
//   support_i = beta_i * ( -S_i x_i + beta_i Y_i ),  S=sum g*alpha, Y=sum g x_j
// hyp_main: grid (64 i-tiles x 16 j-chunks of 64), ~29KB LDS -> 4-5 blocks/CU
//   (whole 1024-block grid co-resident; barriers/latency overlap across blocks).
//   Phase-A B-frags from staged row-major sXJ (proven); phase-B B-frags straight
//   from global fp32 x (lane-contiguous in d), converted in-register -> no
//   transpose staging at all.
// hyp_exp : sums 16 partials + expmap (128 blocks).
// ws floats: Yp[16*131072] | Sp[16*1024]

typedef short short4v __attribute__((ext_vector_type(4)));
typedef short short8v __attribute__((ext_vector_type(8)));
typedef float float4v __attribute__((ext_vector_type(4)));

static __device__ __forceinline__ short f2bf(float f) {
    unsigned u = __float_as_uint(f);
    u += 0x7fff + ((u >> 16) & 1);   // RNE; inputs never NaN here
    return (short)(u >> 16);
}
static __device__ __forceinline__ float bf2f(unsigned short s) {
    return __uint_as_float(((unsigned)s) << 16);
}
static __device__ __forceinline__ float rcpf(float x) { return __builtin_amdgcn_rcpf(x); }
static __device__ __forceinline__ short8v ld8(const unsigned short* p) {
    short4v lo = *(const short4v*)p;        // LDS: two b64 reads (8B-aligned)
    short4v hi = *(const short4v*)(p + 4);
    return (short8v){lo[0],lo[1],lo[2],lo[3],hi[0],hi[1],hi[2],hi[3]};
}
static __device__ __forceinline__ float dot4(float4v a, float4v b) {
    return a[0]*b[0] + a[1]*b[1] + a[2]*b[2] + a[3]*b[3];
}
static __device__ __forceinline__ float atanh_over(float pn) {   // atanh(min(pn,1-eps))/pn
    float uu = fminf(pn, 1.f - 1e-7f);
    return 0.5f * __logf((1.f + uu) * rcpf(1.f - uu)) * rcpf(pn);
}

// ---------------- kernel 1: pairwise MFMA + scalar map ----------------
__global__ __launch_bounds__(256, 4) void hyp_main(
    const float* __restrict__ x, const float* __restrict__ adj,
    const float* __restrict__ battp, const float* __restrict__ w,
    float* __restrict__ Yp, float* __restrict__ Sp)
{
    __shared__ unsigned short sXI[16 * 132];   // X_I bf16 (i, dim)
    __shared__ unsigned short sXJ[64 * 132];   // X_J bf16 (j, dim), this chunk
    __shared__ unsigned short sW [16 * 68];    // g weights bf16 (i, j), pitch 68
    __shared__ float sW2f[128];                // att_w[D:]
    __shared__ float sPx[128], sPr[128];       // j-stat partials (j = slot>>1)
    __shared__ float sPxI[64], sPlI[64];       // i-stat partials (i = slot>>2)
    __shared__ float sX2J[64], sRJ[64];
    __shared__ float sX2I[16], sLI[16];
    __shared__ float sSp[4 * 256];             // per-wave S slots [wave][i*16+n]

    const int t    = threadIdx.x;
    const int lane = t & 63;
    const int wave = t >> 6;
    const int n    = lane & 15;
    const int q    = lane >> 4;
    const int i0   = blockIdx.x * 16;
    const int c    = blockIdx.y;
    const int j0   = c * 64;
    const int jrow = j0 + wave * 16 + n;      // this lane's j (one per lane)
    const float batt = battp[0];

    const float4v* x4 = (const float4v*)x;
    const float4v* w4 = (const float4v*)w;

    // ---- phase 0: issue all independent global loads ----
    // adj for this lane's (4 i-rows, 1 j)
    float adjv[4];
#pragma unroll
    for (int r = 0; r < 4; ++r)
        adjv[r] = adj[(i0 + q * 4 + r) * 1024 + jrow];

    // phase-B B-frags straight from global fp32: B[k=j - j0][d0 + n]
    // fB[nsl][kk][e] = x[(j0 + kk*32 + q*8 + e)*128 + (wave*2+nsl)*16 + n]
    float fB[2][2][8];
#pragma unroll
    for (int nsl = 0; nsl < 2; ++nsl) {
        int d0 = (wave * 2 + nsl) * 16 + n;
#pragma unroll
        for (int kk = 0; kk < 2; ++kk)
#pragma unroll
            for (int e = 0; e < 8; ++e)
                fB[nsl][kk][e] = x[(j0 + kk * 32 + q * 8 + e) * 128 + d0];
    }

    // att_w second half to LDS
    if (t < 32) *(float4v*)&sW2f[t * 4] = w4[32 + t];
    // i-stat partials from global fp32 (64 threads: i=t>>2, quarter=t&3)
    if (t < 64) {
        int i = t >> 2, qt = t & 3;
        float x2p = 0.f, lp = 0.f;
#pragma unroll
        for (int k = 0; k < 8; ++k) {
            float4v v  = x4[(i0 + i) * 32 + qt * 8 + k];
            float4v wv = w4[qt * 8 + k];
            x2p += dot4(v, v);
            lp  += dot4(v, wv);
        }
        sPxI[t] = x2p; sPlI[t] = lp;
    }
    // stage X_I (16x128) fp32->bf16
#pragma unroll
    for (int it = 0; it < 2; ++it) {
        int idx = t + it * 256;
        int r = idx >> 5, cc = idx & 31;
        float4v v = x4[(i0 + r) * 32 + cc];
        short4v h = { f2bf(v[0]), f2bf(v[1]), f2bf(v[2]), f2bf(v[3]) };
        *(short4v*)&sXI[r * 132 + cc * 4] = h;
    }
    // stage X_J (64x128) fp32->bf16, coalesced
#pragma unroll
    for (int it = 0; it < 8; ++it) {
        int idx = t + it * 256;
        int r = idx >> 5, cc = idx & 31;
        float4v v = x4[(j0 + r) * 32 + cc];
        short4v h = { f2bf(v[0]), f2bf(v[1]), f2bf(v[2]), f2bf(v[3]) };
        *(short4v*)&sXJ[r * 132 + cc * 4] = h;
    }
    __syncthreads();   // B1: staging visible

    // ---- j-stats via LDS re-read (128 threads: j=t>>1, half=t&1) ----
    if (t < 128) {
        int j = t >> 1, half = t & 1;
        const unsigned short* rowp = &sXJ[j * 132 + half * 64];
        float x2p = 0.f, rp = 0.f;
#pragma unroll
        for (int k = 0; k < 8; ++k) {
            short8v v = ld8(rowp + k * 8);
#pragma unroll
            for (int e = 0; e < 8; ++e) {
                float f = bf2f((unsigned short)v[e]);
                x2p = fmaf(f, f, x2p);
                rp  = fmaf(f, sW2f[half * 64 + k * 8 + e], rp);
            }
        }
        sPx[t] = x2p; sPr[t] = rp;
    }
    // convert phase-B frags while LDS pass runs (independent)
    short8v bfB[2][2];
#pragma unroll
    for (int nsl = 0; nsl < 2; ++nsl)
#pragma unroll
        for (int kk = 0; kk < 2; ++kk) {
            short8v h;
#pragma unroll
            for (int e = 0; e < 8; ++e) h[e] = f2bf(fB[nsl][kk][e]);
            bfB[nsl][kk] = h;
        }
    __syncthreads();   // B2

    // ---- finalize stats ----
    if (t < 64) {
        float x2 = sPx[2 * t] + sPx[2 * t + 1];
        float r  = sPr[2 * t] + sPr[2 * t + 1];
        float pn = sqrtf(fmaxf(x2, 1e-15f));
        sX2J[t] = x2;
        sRJ[t]  = r * atanh_over(pn);
    } else if (t < 80) {
        int i = t - 64;
        float x2 = sPxI[4*i] + sPxI[4*i+1] + sPxI[4*i+2] + sPxI[4*i+3];
        float l  = sPlI[4*i] + sPlI[4*i+1] + sPlI[4*i+2] + sPlI[4*i+3];
        float pn = sqrtf(fmaxf(x2, 1e-15f));
        sX2I[i] = x2;
        sLI[i]  = l * atanh_over(pn) + batt;   // DenseAtt left + bias
    }
    __syncthreads();   // B3

    // ---- per-lane stats + A-frags ----
    float x2i4[4], bi4[4], li4[4];
#pragma unroll
    for (int r = 0; r < 4; ++r) {
        x2i4[r] = sX2I[q * 4 + r];
        li4[r]  = sLI[q * 4 + r];
        bi4[r]  = 1.f - x2i4[r];
    }
    float x2j = sX2J[wave * 16 + n];
    float rj  = sRJ [wave * 16 + n];
    short8v afrag[4];
#pragma unroll
    for (int kk = 0; kk < 4; ++kk)
        afrag[kk] = ld8(&sXI[n * 132 + kk * 32 + q * 8]);

    // ---- phase A: G = X_I * X_J^T (16x16 per wave, K=128) ----
    float4v acc = (float4v){0.f, 0.f, 0.f, 0.f};
#pragma unroll
    for (int kk = 0; kk < 4; ++kk) {
        short8v b = ld8(&sXJ[(wave * 16 + n) * 132 + kk * 32 + q * 8]);
        acc = __builtin_amdgcn_mfma_f32_16x16x32_bf16(afrag[kk], b, acc, 0, 0, 0);
    }

    // ---- per-pair scalar map -> sW, Sacc ----
    float Sacc[4];
#pragma unroll
    for (int r = 0; r < 4; ++r) {
        float G     = acc[r];
        float alpha = 1.f - 2.f * G + x2j;
        float den   = fmaxf(fmaf(x2i4[r], x2j, 1.f - 2.f * G), 1e-15f);
        float rdn   = rcpf(den);
        float bb    = bi4[r];
        float nn2   = alpha * alpha * x2i4[r] + bb * bb * x2j - 2.f * alpha * bb * G;
        float sn    = sqrtf(fmaxf(nn2 * rdn * rdn, 1e-15f));
        float tt    = atanh_over(sn);
        float z     = li4[r] + rj;
        float sig   = rcpf(1.f + __expf(-z));
        float g     = sig * adjv[r] * tt * rdn;
        Sacc[r]     = g * alpha;
        sW[(q * 4 + r) * 68 + wave * 16 + n] = (unsigned short)f2bf(g);
    }
    __syncthreads();   // B4: sW ready

    // ---- phase B: Y = W(16x64) * X_J(64x128); B-frags already in regs ----
    float4v accB[2];
    accB[0] = (float4v){0.f, 0.f, 0.f, 0.f};
    accB[1] = (float4v){0.f, 0.f, 0.f, 0.f};
#pragma unroll
    for (int nsl = 0; nsl < 2; ++nsl)
#pragma unroll
        for (int kk = 0; kk < 2; ++kk) {
            short8v a = ld8(&sW[n * 68 + kk * 32 + q * 8]);
            accB[nsl] = __builtin_amdgcn_mfma_f32_16x16x32_bf16(a, bfB[nsl][kk], accB[nsl], 0, 0, 0);
        }

    // ---- stores: Y partial + S via per-wave LDS slots ----
    float* Yc = Yp + c * 131072;
#pragma unroll
    for (int nsl = 0; nsl < 2; ++nsl) {
        int d0 = (wave * 2 + nsl) * 16 + n;
#pragma unroll
        for (int r = 0; r < 4; ++r)
            Yc[(i0 + q * 4 + r) * 128 + d0] = accB[nsl][r];
    }
#pragma unroll
    for (int r = 0; r < 4; ++r)
        sSp[wave * 256 + (q * 4 + r) * 16 + n] = Sacc[r];
    __syncthreads();   // B5
    if (t < 16) {
        float s = 0.f;
#pragma unroll
        for (int wv = 0; wv < 4; ++wv)
#pragma unroll
            for (int k4 = 0; k4 < 4; ++k4) {
                float4v v = *(float4v*)&sSp[wv * 256 + t * 16 + k4 * 4];
                s += v[0] + v[1] + v[2] + v[3];
            }
        Sp[c * 1024 + i0 + t] = s;
    }
}

// ---------------- kernel 2: sum partials + expmap ----------------
// 128 blocks x 256 threads: 8 rows/block, 32 lanes/row, 4 dims/lane.
__global__ __launch_bounds__(256) void hyp_exp(
    const float* __restrict__ x, const float* __restrict__ Yp,
    const float* __restrict__ Sp, float* __restrict__ out)
{
    const int t   = threadIdx.x;
    const int row = blockIdx.x * 8 + (t >> 5);
    const int l32 = t & 31;
    float4v y = (float4v){0.f, 0.f, 0.f, 0.f};
    float S = 0.f;
#pragma unroll
    for (int c = 0; c < 16; ++c) {
        y += *(const float4v*)&Yp[c * 131072 + row * 128 + l32 * 4];
        S += Sp[c * 1024 + row];
    }
    float4v xa = ((const float4v*)x)[row * 32 + l32];
    float x2p = dot4(xa, xa);
#pragma unroll
    for (int m = 1; m < 32; m <<= 1) x2p += __shfl_xor(x2p, m, 32);
    float bE = fmaxf(1.f - x2p, 1e-15f);
    float u[4], un2p = 0.f, xup = 0.f;
#pragma unroll
    for (int e = 0; e < 4; ++e) {
        u[e] = bE * (bE * y[e] - S * xa[e]);
        un2p += u[e] * u[e];
        xup  += xa[e] * u[e];
    }
#pragma unroll
    for (int m = 1; m < 32; m <<= 1) {
        un2p += __shfl_xor(un2p, m, 32);
        xup  += __shfl_xor(xup,  m, 32);
    }
    float un  = sqrtf(fmaxf(un2p, 1e-15f));
    float e2  = __expf(2.f * un * rcpf(bE));
    float th  = 1.f - 2.f * rcpf(e2 + 1.f);   // tanh(un/b)
    float s2  = th * rcpf(un);
    float xy  = s2 * xup;
    float y2s = th * th;
    float coef = 1.f + 2.f * xy + y2s;
    float den  = fmaxf(1.f + 2.f * xy + x2p * y2s, 1e-15f);
    float rd   = rcpf(den);
    float4v o = { (coef*xa[0] + bE*s2*u[0])*rd, (coef*xa[1] + bE*s2*u[1])*rd,
                  (coef*xa[2] + bE*s2*u[2])*rd, (coef*xa[3] + bE*s2*u[3])*rd };
    ((float4v*)out)[row * 32 + l32] = o;
}

extern "C" void kernel_launch(void* const* d_in, const int* in_sizes, int n_in,
                              void* d_out, int out_size, void* d_ws, size_t ws_size,
                              hipStream_t stream) {
    const float* x    = (const float*)d_in[0];
    const float* adj  = (const float*)d_in[1];
    const float* w    = (const float*)d_in[2];
    const float* batt = (const float*)d_in[3];
    float* out = (float*)d_out;

    float* Yp = (float*)d_ws;           // 16 * 131072 floats
    float* Sp = Yp + 16 * 131072;       // 16 * 1024 floats

    hipLaunchKernelGGL(hyp_main, dim3(64, 16), dim3(256), 0, stream,
                       x, adj, batt, w, Yp, Sp);
    hipLaunchKernelGGL(hyp_exp, dim3(128), dim3(256), 0, stream, x, Yp, Sp, out);
}

// Round 8
// 72.274 us; speedup vs baseline: 1.0658x; 1.0586x over previous
//
#include <hip/hip_runtime.h>
#include <math.h>

// HypAgg (Poincare ball, c=1), 3 dispatches (dispatches ~free: r2 vs r5).
//   g_ij = att_ij * atanh(sn_ij)/sn_ij / den_ij
//   support_i = beta_i * ( -S_i x_i + beta_i Y_i ),  S=sum g*alpha, Y=sum g x_j
// hyp_stats: per-row x2 / left / right (1024 rows, trivial).
// hyp_main : grid (64 i-tiles x 8 j-chunks of 128), 2 blocks/CU, only TWO
//   barriers (staging, sW). Stats prefetched to regs; S partials go straight
//   to global (no in-block reduction).
// hyp_exp  : sums 8 Y partials + 512 S partials per row + expmap (128 blocks).
// ws floats: Yp[8*131072] | Sp2[8*1024*64] | st_x2[1024] | st_L[1024] | st_R[1024]

typedef short short4v __attribute__((ext_vector_type(4)));
typedef short short8v __attribute__((ext_vector_type(8)));
typedef float float4v __attribute__((ext_vector_type(4)));

static __device__ __forceinline__ short f2bf(float f) {
    unsigned u = __float_as_uint(f);
    u += 0x7fff + ((u >> 16) & 1);   // RNE; inputs never NaN here
    return (short)(u >> 16);
}
static __device__ __forceinline__ float rcpf(float x) { return __builtin_amdgcn_rcpf(x); }
static __device__ __forceinline__ short8v ld8(const unsigned short* p) {
    short4v lo = *(const short4v*)p;        // LDS: two b64 reads (8B-aligned)
    short4v hi = *(const short4v*)(p + 4);
    return (short8v){lo[0],lo[1],lo[2],lo[3],hi[0],hi[1],hi[2],hi[3]};
}
static __device__ __forceinline__ float dot4(float4v a, float4v b) {
    return a[0]*b[0] + a[1]*b[1] + a[2]*b[2] + a[3]*b[3];
}
static __device__ __forceinline__ float atanh_over(float pn) {   // atanh(min(pn,1-eps))/pn
    float uu = fminf(pn, 1.f - 1e-7f);
    return 0.5f * __logf((1.f + uu) * rcpf(1.f - uu)) * rcpf(pn);
}

// ---------------- kernel 1: per-row stats ----------------
__global__ __launch_bounds__(256) void hyp_stats(
    const float* __restrict__ x, const float* __restrict__ w,
    const float* __restrict__ battp,
    float* __restrict__ st_x2, float* __restrict__ st_L, float* __restrict__ st_R)
{
    int row  = blockIdx.x * 4 + (threadIdx.x >> 6);
    int lane = threadIdx.x & 63;
    const float* xr = x + row * 128;
    float a0 = xr[lane], a1 = xr[lane + 64];
    float x2 = a0 * a0 + a1 * a1;
    float dl = a0 * w[lane]       + a1 * w[lane + 64];
    float dr = a0 * w[lane + 128] + a1 * w[lane + 192];
    for (int m = 1; m < 64; m <<= 1) {
        x2 += __shfl_xor(x2, m);
        dl += __shfl_xor(dl, m);
        dr += __shfl_xor(dr, m);
    }
    if (lane == 0) {
        float pn = sqrtf(fmaxf(x2, 1e-15f));
        float f  = atanh_over(pn);
        st_x2[row] = x2;
        st_L[row]  = f * dl + battp[0];   // DenseAtt left + bias folded
        st_R[row]  = f * dr;
    }
}

// ---------------- kernel 2: pairwise MFMA + scalar map (2 barriers) ----------------
__global__ __launch_bounds__(256, 2) void hyp_main(
    const float* __restrict__ x, const float* __restrict__ adj,
    const float* __restrict__ st_x2, const float* __restrict__ st_L,
    const float* __restrict__ st_R,
    float* __restrict__ Yp, float* __restrict__ Sp2)
{
    __shared__ unsigned short sXI [16 * 132];   // X_I  bf16 (i, dim)
    __shared__ unsigned short sXJ [128 * 132];  // X_J  bf16 (j, dim)
    __shared__ unsigned short sXJt[128 * 132];  // X_J^T bf16 (dim, j)
    __shared__ unsigned short sW  [16 * 132];   // g weights bf16 (i, j)

    const int t    = threadIdx.x;
    const int lane = t & 63;
    const int wave = t >> 6;
    const int n    = lane & 15;
    const int q    = lane >> 4;
    const int i0   = blockIdx.x * 16;
    const int c    = blockIdx.y;
    const int j0   = c * 128;

    const float4v* x4 = (const float4v*)x;

    // ---- register prefetch (independent; overlaps staging) ----
    float x2i4[4], bi4[4], li4[4];
#pragma unroll
    for (int r = 0; r < 4; ++r) {
        int i = i0 + q * 4 + r;
        x2i4[r] = st_x2[i];
        li4[r]  = st_L[i];
    }
    float x2j2[2], rj2[2], adjv[2][4];
#pragma unroll
    for (int jsl = 0; jsl < 2; ++jsl) {
        int j = j0 + (wave * 2 + jsl) * 16 + n;
        x2j2[jsl] = st_x2[j];
        rj2[jsl]  = st_R[j];
#pragma unroll
        for (int r = 0; r < 4; ++r)
            adjv[jsl][r] = adj[(i0 + q * 4 + r) * 1024 + j];
    }
#pragma unroll
    for (int r = 0; r < 4; ++r) bi4[r] = 1.f - x2i4[r];

    // ---- stage X_I (16x128) fp32->bf16 ----
#pragma unroll
    for (int it = 0; it < 2; ++it) {
        int idx = t + it * 256;
        int r = idx >> 5, cc = idx & 31;
        float4v v = x4[(i0 + r) * 32 + cc];
        short4v h = { f2bf(v[0]), f2bf(v[1]), f2bf(v[2]), f2bf(v[3]) };
        *(short4v*)&sXI[r * 132 + cc * 4] = h;
    }
    // ---- stage X_J row-major + transposed via 4x4 micro-blocks ----
    // bid bits: [0..3]=dcL, [4..5]=jrL, [6..8]=jrH, [9]=dcH
#pragma unroll
    for (int it = 0; it < 4; ++it) {
        int bid = t + it * 256;
        int jr = ((bid >> 4) & 3) | (((bid >> 6) & 7) << 2);   // 0..31
        int dc = (bid & 15) | (((bid >> 9) & 1) << 4);         // 0..31
        float4v v[4];
#pragma unroll
        for (int e = 0; e < 4; ++e)
            v[e] = x4[(j0 + jr * 4 + e) * 32 + dc];
        short4v h[4];
#pragma unroll
        for (int e = 0; e < 4; ++e) {
            h[e] = (short4v){ f2bf(v[e][0]), f2bf(v[e][1]), f2bf(v[e][2]), f2bf(v[e][3]) };
            *(short4v*)&sXJ[(jr * 4 + e) * 132 + dc * 4] = h[e];
        }
#pragma unroll
        for (int d = 0; d < 4; ++d) {
            short4v ht = (short4v){ h[0][d], h[1][d], h[2][d], h[3][d] };
            *(short4v*)&sXJt[(dc * 4 + d) * 132 + jr * 4] = ht;
        }
    }
    __syncthreads();   // B1: staging visible

    // ---- A-frags ----
    short8v afrag[4];
#pragma unroll
    for (int kk = 0; kk < 4; ++kk)
        afrag[kk] = ld8(&sXI[n * 132 + kk * 32 + q * 8]);

    float Sacc[4] = {0.f, 0.f, 0.f, 0.f};

    // ---- phase A: G = X_I * X_J^T + scalar map -> sW, Sacc ----
#pragma unroll
    for (int jsl = 0; jsl < 2; ++jsl) {
        int js = wave * 2 + jsl;
        int jrow = js * 16 + n;
        float4v acc = (float4v){0.f, 0.f, 0.f, 0.f};
#pragma unroll
        for (int kk = 0; kk < 4; ++kk) {
            short8v b = ld8(&sXJ[jrow * 132 + kk * 32 + q * 8]);
            acc = __builtin_amdgcn_mfma_f32_16x16x32_bf16(afrag[kk], b, acc, 0, 0, 0);
        }
        float x2j = x2j2[jsl];
        float rj  = rj2[jsl];
#pragma unroll
        for (int r = 0; r < 4; ++r) {
            float G     = acc[r];
            int   i     = q * 4 + r;
            float alpha = 1.f - 2.f * G + x2j;
            float den   = fmaxf(fmaf(x2i4[r], x2j, 1.f - 2.f * G), 1e-15f);
            float rdn   = rcpf(den);
            float bb    = bi4[r];
            float nn2   = alpha * alpha * x2i4[r] + bb * bb * x2j - 2.f * alpha * bb * G;
            float sn    = sqrtf(fmaxf(nn2 * rdn * rdn, 1e-15f));
            float tt    = atanh_over(sn);
            float z     = li4[r] + rj;
            float sig   = rcpf(1.f + __expf(-z));
            float g     = sig * adjv[jsl][r] * tt * rdn;
            Sacc[r]     = fmaf(g, alpha, Sacc[r]);
            sW[i * 132 + js * 16 + n] = (unsigned short)f2bf(g);
        }
    }
    __syncthreads();   // B2: sW ready

    // ---- phase B: Y = W(16x128) * X_J(128x128) via sXJt ----
    float4v accB[2];
    accB[0] = (float4v){0.f, 0.f, 0.f, 0.f};
    accB[1] = (float4v){0.f, 0.f, 0.f, 0.f};
#pragma unroll
    for (int nsl = 0; nsl < 2; ++nsl) {
        int ns = wave * 2 + nsl;
#pragma unroll
        for (int kk = 0; kk < 4; ++kk) {
            short8v a = ld8(&sW  [n * 132 + kk * 32 + q * 8]);
            short8v b = ld8(&sXJt[(ns * 16 + n) * 132 + kk * 32 + q * 8]);
            accB[nsl] = __builtin_amdgcn_mfma_f32_16x16x32_bf16(a, b, accB[nsl], 0, 0, 0);
        }
    }

    // ---- stores: Y partials + raw S partials (no reduction, no barrier) ----
    float* Yc = Yp + c * 131072;
#pragma unroll
    for (int nsl = 0; nsl < 2; ++nsl) {
        int ns = wave * 2 + nsl;
#pragma unroll
        for (int r = 0; r < 4; ++r)
            Yc[(i0 + q * 4 + r) * 128 + ns * 16 + n] = accB[nsl][r];
    }
    // Sp2[c][row][wave][n]: 64 partials per (chunk,row)
#pragma unroll
    for (int r = 0; r < 4; ++r)
        Sp2[((c * 1024 + i0 + q * 4 + r) * 4 + wave) * 16 + n] = Sacc[r];
}

// ---------------- kernel 3: sum partials + expmap ----------------
// 128 blocks x 256 threads: 8 rows/block, 32 lanes/row, 4 dims/lane.
__global__ __launch_bounds__(256) void hyp_exp(
    const float* __restrict__ x, const float* __restrict__ Yp,
    const float* __restrict__ Sp2, const float* __restrict__ st_x2,
    float* __restrict__ out)
{
    const int t   = threadIdx.x;
    const int row = blockIdx.x * 8 + (t >> 5);
    const int l32 = t & 31;
    float4v y = (float4v){0.f, 0.f, 0.f, 0.f};
    float S = 0.f;
#pragma unroll
    for (int c = 0; c < 8; ++c) {
        y += *(const float4v*)&Yp[c * 131072 + row * 128 + l32 * 4];
        S += Sp2[(c * 1024 + row) * 64 + l32];
        S += Sp2[(c * 1024 + row) * 64 + 32 + l32];
    }
#pragma unroll
    for (int m = 1; m < 32; m <<= 1) S += __shfl_xor(S, m, 32);

    float4v xa = ((const float4v*)x)[row * 32 + l32];
    float x2 = st_x2[row];
    float bE = fmaxf(1.f - x2, 1e-15f);
    float u[4], un2p = 0.f, xup = 0.f;
#pragma unroll
    for (int e = 0; e < 4; ++e) {
        u[e] = bE * (bE * y[e] - S * xa[e]);
        un2p += u[e] * u[e];
        xup  += xa[e] * u[e];
    }
#pragma unroll
    for (int m = 1; m < 32; m <<= 1) {
        un2p += __shfl_xor(un2p, m, 32);
        xup  += __shfl_xor(xup,  m, 32);
    }
    float un  = sqrtf(fmaxf(un2p, 1e-15f));
    float e2  = __expf(2.f * un * rcpf(bE));
    float th  = 1.f - 2.f * rcpf(e2 + 1.f);   // tanh(un/b)
    float s2  = th * rcpf(un);
    float xy  = s2 * xup;
    float y2s = th * th;
    float coef = 1.f + 2.f * xy + y2s;
    float den  = fmaxf(1.f + 2.f * xy + x2 * y2s, 1e-15f);
    float rd   = rcpf(den);
    float4v o = { (coef*xa[0] + bE*s2*u[0])*rd, (coef*xa[1] + bE*s2*u[1])*rd,
                  (coef*xa[2] + bE*s2*u[2])*rd, (coef*xa[3] + bE*s2*u[3])*rd };
    ((float4v*)out)[row * 32 + l32] = o;
}

extern "C" void kernel_launch(void* const* d_in, const int* in_sizes, int n_in,
                              void* d_out, int out_size, void* d_ws, size_t ws_size,
                              hipStream_t stream) {
    const float* x    = (const float*)d_in[0];
    const float* adj  = (const float*)d_in[1];
    const float* w    = (const float*)d_in[2];
    const float* batt = (const float*)d_in[3];
    float* out = (float*)d_out;

    float* Yp    = (float*)d_ws;            // 8 * 131072 floats
    float* Sp2   = Yp + 8 * 131072;         // 8 * 1024 * 64 floats (2 MB)
    float* st_x2 = Sp2 + 8 * 1024 * 64;     // 1024
    float* st_L  = st_x2 + 1024;            // 1024
    float* st_R  = st_L + 1024;             // 1024

    hipLaunchKernelGGL(hyp_stats, dim3(256), dim3(256), 0, stream,
                       x, w, batt, st_x2, st_L, st_R);
    hipLaunchKernelGGL(hyp_main, dim3(64, 8), dim3(256), 0, stream,
                       x, adj, st_x2, st_L, st_R, Yp, Sp2);
    hipLaunchKernelGGL(hyp_exp, dim3(128), dim3(256), 0, stream,
                       x, Yp, Sp2, st_x2, out);
}